// Round 8
// baseline (392.688 us; speedup 1.0000x reference)
//
#include <hip/hip_runtime.h>

// MultiHeadAttentionBlock: B=4, S=2048, D=1024, H=16, DK=64
// Pipeline: cvt_w (weights only); gemm_qkv reads q/k/v fp32 DIRECTLY with
// fused in-staging bf16 conversion (saves cvt_all's 168 MB round trip);
// flash attention (R3 proven); gemm_out (256x128 8-phase) -> fp32.
// All matmuls: bf16 MFMA 16x16x32, fp32 accumulate.
//
// Verified MFMA layouts (learn_hip m89/m91):
//   A-operand: lane holds A[m=lane&15][k=(lane>>4)*8 + j], j=0..7 (16B contiguous)
//   B-operand: lane holds B^T-row n=lane&15 along k (same shape as A)
//   C/D:       col = lane&15 (B index), row = (lane>>4)*4 + reg (A index)

typedef __attribute__((ext_vector_type(8))) short bf16x8;
typedef __attribute__((ext_vector_type(4))) float f32x4;
typedef unsigned int u32;

#define DEVI __device__ __forceinline__

static constexpr int S_LEN = 2048;
static constexpr int NH = 16;
static constexpr int DK = 64;
// scores scale folded into Q projection: (1/sqrt(64)) * log2(e)
static constexpr float Q_SCALE = 0.125f * 1.44269504088896340736f;

DEVI unsigned short f2b(float f) {  // fp32 -> bf16 round-to-nearest-even
    unsigned int u = __builtin_bit_cast(unsigned int, f);
    u += 0x7fffu + ((u >> 16) & 1u);
    return (unsigned short)(u >> 16);
}

DEVI u32 pkbf16(float a, float b) {
#if __has_builtin(__builtin_amdgcn_cvt_pk_bf16_f32)
    auto r = __builtin_amdgcn_cvt_pk_bf16_f32(a, b);
    return __builtin_bit_cast(u32, r);
#else
    return (u32)f2b(a) | ((u32)f2b(b) << 16);
#endif
}

// raw v_exp_f32 (no OCML fixup; softmax weights tolerate denormal flush)
DEVI float fexp2(float x) {
#if __has_builtin(__builtin_amdgcn_exp2f)
    return __builtin_amdgcn_exp2f(x);
#else
    return exp2f(x);
#endif
}

DEVI f32x4 mfma16(bf16x8 a, bf16x8 b, f32x4 c) {
    return __builtin_amdgcn_mfma_f32_16x16x32_bf16(a, b, c, 0, 0, 0);
}

#define GLL16(g, l)                                                        \
    __builtin_amdgcn_global_load_lds(                                      \
        (const __attribute__((address_space(1))) u32*)(g),                 \
        (__attribute__((address_space(3))) u32*)(l), 16, 0, 0)

#define SBAR __builtin_amdgcn_sched_barrier(0)
#define PHB  SBAR; __builtin_amdgcn_s_barrier(); SBAR
#define LGKM0 asm volatile("s_waitcnt lgkmcnt(0)" ::: "memory")

// ---------------------------------------------------------------------------
// fp32 -> bf16 converter for the 4 weight matrices (16 MB fp32, ~4 us)
// ---------------------------------------------------------------------------
__global__ __launch_bounds__(256) void cvt_w(
    const float* __restrict__ a, const float* __restrict__ b,
    const float* __restrict__ c, const float* __restrict__ d,
    unsigned short* __restrict__ o) {
    const float* src = blockIdx.y == 0 ? a : blockIdx.y == 1 ? b
                     : blockIdx.y == 2 ? c : d;
    unsigned short* dst = o + (long)blockIdx.y * 1048576;
    long i = ((long)blockIdx.x * 256 + threadIdx.x) * 8;
    float4 v0 = *(const float4*)(src + i);
    float4 v1 = *(const float4*)(src + i + 4);
    uint4 ov;
    ov.x = pkbf16(v0.x, v0.y);
    ov.y = pkbf16(v0.z, v0.w);
    ov.z = pkbf16(v1.x, v1.y);
    ov.w = pkbf16(v1.z, v1.w);
    *(uint4*)(dst + i) = ov;
}

// ---------------------------------------------------------------------------
// Shared GEMM geometry: 256x128 tile, BK=64, 8 waves (2M x 4N), per-wave
// output 128x32, acc[8][2]. LDS 96 KiB. MFMA cluster = 16/phase.
// ---------------------------------------------------------------------------
#define MM16(MH)                                                           \
    __builtin_amdgcn_s_setprio(1);                                         \
    _Pragma("unroll") for (int mi = 0; mi < 4; ++mi)                       \
        _Pragma("unroll") for (int ni = 0; ni < 2; ++ni)                   \
            _Pragma("unroll") for (int kk = 0; kk < 2; ++kk)               \
                acc[(MH)*4 + mi][ni] = mfma16(                             \
                    a[mi][kk], b[ni][kk], acc[(MH)*4 + mi][ni]);           \
    __builtin_amdgcn_s_setprio(0);

// ---------------------------------------------------------------------------
// bf16-A core (gemm_out). R7-proven schedule, unchanged:
// ph1 stages B(t1),Ac1(t1); ph2 Ac0(t2) + vmcnt(2); ph3 B(t2),Ac1(t2);
// ph4 Ac0(t3) + vmcnt(2). Consumption-defined chunks; FIFO-walked.
// ---------------------------------------------------------------------------
DEVI void gemm_core(const unsigned short* __restrict__ Am,
                    const unsigned short* __restrict__ Wm,
                    int m0, int n0, int tid, f32x4 (&acc)[8][2]) {
    __shared__ __align__(16) unsigned short As[2][256 * 64];
    __shared__ __align__(16) unsigned short Bs[2][128 * 64];
    const int wid = tid >> 6, l = tid & 63, l16 = l & 15, quad = l >> 4;
    const int swz = l16 & 7;
    const int wm = (wid >> 2) * 128, wn = (wid & 3) * 32;
    unsigned short *As0 = &As[0][0], *As1 = &As[1][0];
    unsigned short *Bs0 = &Bs[0][0], *Bs1 = &Bs[1][0];

    bf16x8 a[4][2], b[2][2];

    auto stg = [&](const unsigned short* Mat, int r0, int ko,
                   unsigned short* lds, int type) {
        #pragma unroll
        for (int pass = 0; pass < 2; ++pass) {
            int wlr = pass * 64 + wid * 8;
            int row0 = type == 0 ? (wlr < 64 ? wlr : wlr + 64)
                     : type == 1 ? 64 + (wlr < 64 ? wlr : wlr + 64)
                                 : wlr;
            int row = row0 + (l >> 3);
            int cl = (l & 7) ^ (l >> 3);
            GLL16(Mat + (long)(r0 + row) * 1024 + ko + cl * 8, lds + row0 * 64);
        }
    };
    auto lda = [&](const unsigned short* as, int mh) {
        #pragma unroll
        for (int mi = 0; mi < 4; ++mi)
            #pragma unroll
            for (int kk = 0; kk < 2; ++kk)
                a[mi][kk] = *(const bf16x8*)(as +
                    (wm + (mh * 4 + mi) * 16 + l16) * 64 +
                    (((kk * 4 + quad) ^ swz) << 3));
    };
    auto ldb = [&](const unsigned short* bs) {
        #pragma unroll
        for (int ni = 0; ni < 2; ++ni)
            #pragma unroll
            for (int kk = 0; kk < 2; ++kk)
                b[ni][kk] = *(const bf16x8*)(bs +
                    (wn + ni * 16 + l16) * 64 +
                    (((kk * 4 + quad) ^ swz) << 3));
    };

    stg(Am, m0, 0, As0, 0);
    stg(Wm, n0, 0, Bs0, 2);
    stg(Am, m0, 0, As0, 1);
    stg(Am, m0, 64, As1, 0);
    asm volatile("s_waitcnt vmcnt(2)" ::: "memory");
    __builtin_amdgcn_s_barrier(); SBAR;

    #pragma unroll 1
    for (int it = 0; it < 8; ++it) {
        const bool F = it < 7;
        const int ko1 = it * 128 + 64, ko2 = it * 128 + 128, ko3 = it * 128 + 192;
        lda(As0, 0); ldb(Bs0);
        stg(Wm, n0, ko1, Bs1, 2);
        stg(Am, m0, ko1, As1, 1);
        PHB; MM16(0); PHB;
        lda(As0, 1);
        if (F) stg(Am, m0, ko2, As0, 0);
        PHB; MM16(1);
        SBAR;
        if (F) { asm volatile("s_waitcnt vmcnt(2)" ::: "memory"); }
        else   { asm volatile("s_waitcnt vmcnt(0)" ::: "memory"); }
        __builtin_amdgcn_s_barrier(); SBAR;
        lda(As1, 0); ldb(Bs1);
        if (F) { stg(Wm, n0, ko2, Bs0, 2); stg(Am, m0, ko2, As0, 1); }
        PHB; MM16(0); PHB;
        lda(As1, 1);
        if (F) stg(Am, m0, ko3, As1, 0);
        PHB; MM16(1);
        SBAR;
        if (F) { asm volatile("s_waitcnt vmcnt(2)" ::: "memory"); }
        __builtin_amdgcn_s_barrier(); SBAR;
    }
}

// ---------------------------------------------------------------------------
// fp32-A core (gemm_qkv): A staged via reg (global fp32 -> cvt_pk -> ds_write
// into the IDENTICAL swizzled LDS image), B via GLL16. Saves the cvt_all
// pass (168 MB) at +48 MB fp32 A reads (L2-hot across the 8 n0-blocks/XCD).
//
// Write/consume schedule (all FIFO-walked; writes land >=1 barrier before
// their consumer, >=1 barrier after the previous reader of the region):
//   writes: ph1 As1-Ac1(t1) | ph2 As0-Ac0(t2) | ph3 As0-Ac1(t2) | ph4 As1-Ac0(t3)
//   issues (1 phase ahead): ph1 Ac0(t2)->rgA | ph2 Ac1(t2)->rgB
//                           ph3 Ac0(t3)->rgA | ph4 Ac1(t3)->rgB
//   B GLL16: ph1 B(t1)->Bs1 (read ph3) | ph3 B(t2)->Bs0 (read next ph1)
// Compiler auto-vmcnt before each wrA's register use retires that A-load
// group (and any older, incl. B - harmless early retire). Explicit boundary
// waits keep only the newest A-group in flight:
//   end-ph2: vmcnt(4) retires ph1-B2 (Bs1 read at ph3); leaves ph2-A4.
//   end-ph4: vmcnt(4) retires ph3-B2 (Bs0 read next ph1); leaves ph4-A4.
// LGKM0 before each pre-MFMA barrier commits ds_writes for cross-wave reads.
// Prologue: issue A(t0)x2+B(t0), write As0; issue Ac0(t1), write As1-Ac0
// (its auto-wait retires B(t0) - needed at ph1 anyway); issue Ac1(t1);
// LGKM0+barrier. Tail it=7: guards drop t16/t17; end-ph2 vmcnt(0).
// ---------------------------------------------------------------------------
DEVI void gemm_core_f32a(const float* __restrict__ Am,
                         const unsigned short* __restrict__ Wm,
                         int m0, int n0, int tid, f32x4 (&acc)[8][2]) {
    __shared__ __align__(16) unsigned short As[2][256 * 64];
    __shared__ __align__(16) unsigned short Bs[2][128 * 64];
    const int wid = tid >> 6, l = tid & 63, l16 = l & 15, quad = l >> 4;
    const int swz = l16 & 7;
    const int wm = (wid >> 2) * 128, wn = (wid & 3) * 32;
    unsigned short *As0 = &As[0][0], *As1 = &As[1][0];
    unsigned short *Bs0 = &Bs[0][0], *Bs1 = &Bs[1][0];

    bf16x8 a[4][2], b[2][2];
    float4 rgA[2][2], rgB[2][2];  // named A-load buffers (rule #20)

    // issue fp32 loads for one A chunk (type 0=Ac0 rows{0-63,128-191},
    // 1=Ac1 rows{64-127,192-255}); thread covers (row0+(l>>3), cl=(l&7)^(l>>3))
    auto issA = [&](int ko, int type, float4 (&rg)[2][2]) {
        #pragma unroll
        for (int pass = 0; pass < 2; ++pass) {
            int wlr = pass * 64 + wid * 8;
            int row0 = (type ? 64 : 0) + (wlr < 64 ? wlr : wlr + 64);
            int row = row0 + (l >> 3);
            int cl = (l & 7) ^ (l >> 3);
            const float* p = Am + (long)(m0 + row) * 1024 + ko + cl * 8;
            rg[pass][0] = *(const float4*)(p);
            rg[pass][1] = *(const float4*)(p + 4);
        }
    };
    // convert + ds_write_b128 to the same dest GLL16 would use (lane l at
    // byte l*16 of the chunk's linear region)
    auto wrA = [&](unsigned short* lds, int type, float4 (&rg)[2][2]) {
        #pragma unroll
        for (int pass = 0; pass < 2; ++pass) {
            int wlr = pass * 64 + wid * 8;
            int row0 = (type ? 64 : 0) + (wlr < 64 ? wlr : wlr + 64);
            uint4 o;
            o.x = pkbf16(rg[pass][0].x, rg[pass][0].y);
            o.y = pkbf16(rg[pass][0].z, rg[pass][0].w);
            o.z = pkbf16(rg[pass][1].x, rg[pass][1].y);
            o.w = pkbf16(rg[pass][1].z, rg[pass][1].w);
            *(uint4*)(lds + row0 * 64 + l * 8) = o;
        }
    };
    auto stgB = [&](int ko, unsigned short* lds) {
        #pragma unroll
        for (int pass = 0; pass < 2; ++pass) {
            int wlr = pass * 64 + wid * 8;
            int row = wlr + (l >> 3);
            int cl = (l & 7) ^ (l >> 3);
            GLL16(Wm + (long)(n0 + row) * 1024 + ko + cl * 8, lds + wlr * 64);
        }
    };
    auto lda = [&](const unsigned short* as, int mh) {
        #pragma unroll
        for (int mi = 0; mi < 4; ++mi)
            #pragma unroll
            for (int kk = 0; kk < 2; ++kk)
                a[mi][kk] = *(const bf16x8*)(as +
                    (wm + (mh * 4 + mi) * 16 + l16) * 64 +
                    (((kk * 4 + quad) ^ swz) << 3));
    };
    auto ldb = [&](const unsigned short* bs) {
        #pragma unroll
        for (int ni = 0; ni < 2; ++ni)
            #pragma unroll
            for (int kk = 0; kk < 2; ++kk)
                b[ni][kk] = *(const bf16x8*)(bs +
                    (wn + ni * 16 + l16) * 64 +
                    (((kk * 4 + quad) ^ swz) << 3));
    };

    // prologue (FIFO: A4a,A4b,B2, [waits a,b], A4d [wait d retires B2], A4e)
    issA(0, 0, rgA);
    issA(0, 1, rgB);
    stgB(0, Bs0);
    wrA(As0, 0, rgA);
    wrA(As0, 1, rgB);
    issA(64, 0, rgA);          // Ac0(t1)
    wrA(As1, 0, rgA);          // auto-wait retires B(t0) too (needed ph1)
    issA(64, 1, rgB);          // Ac1(t1) -> written at ph1
    LGKM0;
    __builtin_amdgcn_s_barrier(); SBAR;

    #pragma unroll 1
    for (int it = 0; it < 8; ++it) {
        const bool F = it < 7;
        const int ko1 = it * 128 + 64, ko2 = it * 128 + 128, ko3 = it * 128 + 192;
        // ph1: compute t0-mh0 (reads As0-Ac0, Bs0)
        wrA(As1, 1, rgB);                  // Ac1(t1); auto-wait on rgB
        if (F) issA(ko2, 0, rgA);          // Ac0(t2)
        stgB(ko1, Bs1);                    // B(t1), read ph3
        lda(As0, 0); ldb(Bs0);
        LGKM0;
        PHB; MM16(0); PHB;
        // ph2: t0-mh1
        if (F) { wrA(As0, 0, rgA); issA(ko2, 1, rgB); }
        lda(As0, 1);
        LGKM0;
        PHB; MM16(1);
        SBAR;
        if (F) { asm volatile("s_waitcnt vmcnt(4)" ::: "memory"); }
        else   { asm volatile("s_waitcnt vmcnt(0)" ::: "memory"); }
        __builtin_amdgcn_s_barrier(); SBAR;
        // ph3: t1-mh0 (reads As1-Ac0, Bs1)
        if (F) { wrA(As0, 1, rgB); issA(ko3, 0, rgA); stgB(ko2, Bs0); }
        lda(As1, 0); ldb(Bs1);
        LGKM0;
        PHB; MM16(0); PHB;
        // ph4: t1-mh1 (reads As1-Ac1)
        if (F) { wrA(As1, 0, rgA); issA(ko3, 1, rgB); }
        lda(As1, 1);
        LGKM0;
        PHB; MM16(1);
        SBAR;
        if (F) { asm volatile("s_waitcnt vmcnt(4)" ::: "memory"); }
        __builtin_amdgcn_s_barrier(); SBAR;
    }
}

// XCD swizzle for 256-block planes (256 % 8 == 0, bijective)
DEVI void gemm_bid(int& m0, int& n0) {
    int bid = blockIdx.y * 8 + blockIdx.x;
    int b2 = (bid & 7) * 32 + (bid >> 3);
    m0 = (b2 >> 3) * 256;
    n0 = (b2 & 7) * 128;
}

// ---------------------------------------------------------------------------
// Batched QKV GEMM (fp32 A): z=0: qh=(q@wq^T+bq)*Q_SCALE  [B,H,S,DK]
//                            z=1: kh= k@wk^T+bk           [B,H,S,DK]
//                            z=2: vht=(v@wv^T+bv)^T       [B,H,DK,S]
// ---------------------------------------------------------------------------
__global__ __launch_bounds__(512, 2) void gemm_qkv(
    const float* __restrict__ q, const float* __restrict__ k,
    const float* __restrict__ v, const unsigned short* __restrict__ wqkv,
    const float* __restrict__ bq, const float* __restrict__ bk,
    const float* __restrict__ bv, unsigned short* __restrict__ qh,
    unsigned short* __restrict__ kh, unsigned short* __restrict__ vht) {
    const int tid = threadIdx.x;
    const int wid = tid >> 6, l = tid & 63, l16 = l & 15, quad = l >> 4;
    const int wm = (wid >> 2) * 128, wn = (wid & 3) * 32;
    int m0, n0;
    gemm_bid(m0, n0);
    const int z = blockIdx.z;
    const float* Am = z == 0 ? q : z == 1 ? k : v;
    const unsigned short* Wm = wqkv + (long)z * 1048576;
    const float* bias = z == 0 ? bq : z == 1 ? bk : bv;

    f32x4 acc[8][2] = {};
    gemm_core_f32a(Am, Wm, m0, n0, tid, acc);

    if (z < 2) {
        unsigned short* out = z == 0 ? qh : kh;
        const float scale = z == 0 ? Q_SCALE : 1.0f;
        #pragma unroll
        for (int ni = 0; ni < 2; ++ni) {
            int n = n0 + wn + ni * 16 + l16;
            float bvl = bias[n];
            int hh = n >> 6, dd = n & 63;
            #pragma unroll
            for (int mi = 0; mi < 8; ++mi)
                #pragma unroll
                for (int r = 0; r < 4; ++r) {
                    int m = m0 + wm + mi * 16 + quad * 4 + r;
                    int bb = m >> 11, ss = m & 2047;
                    out[(((long)(bb * NH + hh) * S_LEN + ss) * DK) + dd] =
                        f2b((acc[mi][ni][r] + bvl) * scale);
                }
        }
    } else {
        #pragma unroll
        for (int ni = 0; ni < 2; ++ni) {
            int n = n0 + wn + ni * 16 + l16;
            float bvl = bias[n];
            int hh = n >> 6, dd = n & 63;
            #pragma unroll
            for (int mi = 0; mi < 8; ++mi) {
                int m = m0 + wm + mi * 16 + quad * 4;  // r contiguous in s
                int bb = m >> 11, ss = m & 2047;
                uint2 pk;
                pk.x = pkbf16(acc[mi][ni][0] + bvl, acc[mi][ni][1] + bvl);
                pk.y = pkbf16(acc[mi][ni][2] + bvl, acc[mi][ni][3] + bvl);
                *(uint2*)(vht + ((long)(bb * NH + hh) * DK + dd) * S_LEN + ss) = pk;
            }
        }
    }
}

// ---------------------------------------------------------------------------
// Output GEMM: fp32 out[m,n] = ctx@wo^T + bo  (bf16 core, unchanged)
// ---------------------------------------------------------------------------
__global__ __launch_bounds__(512, 2) void gemm_out(
    const unsigned short* __restrict__ A, const unsigned short* __restrict__ W,
    const float* __restrict__ bias, float* __restrict__ out) {
    const int tid = threadIdx.x;
    const int wid = tid >> 6, l = tid & 63, l16 = l & 15, quad = l >> 4;
    const int wm = (wid >> 2) * 128, wn = (wid & 3) * 32;
    int m0, n0;
    gemm_bid(m0, n0);

    f32x4 acc[8][2] = {};
    gemm_core(A, W, m0, n0, tid, acc);

    #pragma unroll
    for (int ni = 0; ni < 2; ++ni) {
        int n = n0 + wn + ni * 16 + l16;
        float bv = bias[n];
        #pragma unroll
        for (int mi = 0; mi < 8; ++mi)
            #pragma unroll
            for (int r = 0; r < 4; ++r) {
                int m = m0 + wm + mi * 16 + quad * 4 + r;
                out[(long)m * 1024 + n] = acc[mi][ni][r] + bv;
            }
    }
}

// ---------------------------------------------------------------------------
// Flash attention — R3 version verbatim (stable 108.9-111.3 us).
// Transposed formulation: S^T = K.Q^T; p = exp2(s); P via wave-private LDS
// rows; O^T = V^T.P^T; lsum via ones-vector MFMA; K dbuf staged 1 ahead,
// V tri-buf staged 2 ahead; counted vmcnt(2) + raw barrier once per kt.
// LDS: 16384 (Kb x2) + 24576 (Vb x3) + 11264 (P) = 52224 B -> 3 blocks/CU.
// ---------------------------------------------------------------------------
__global__ __launch_bounds__(256, 3) void attn(
    const unsigned short* __restrict__ qh, const unsigned short* __restrict__ kh,
    const unsigned short* __restrict__ vht, unsigned short* __restrict__ ctx) {
    __shared__ __align__(16) unsigned short Kb[2][4096];   // [64 keys][64 d] swz
    __shared__ __align__(16) unsigned short Vb[3][4096];   // [64 d][64 keys] swz
    __shared__ __align__(16) unsigned short P[128 * 44];

    // XCD-aware swizzle: 1024 blocks, bijective; 128 blocks/XCD = 8 heads
    // x 16 q-tiles (head's K/V panel L2-resident). R1: FETCH 139->32 MB.
    const int id = blockIdx.y * 16 + blockIdx.x;
    const int id2 = (id & 7) * 128 + (id >> 3);
    const int qt = id2 & 15, bh = id2 >> 4;
    const int tid = threadIdx.x;
    const int w = tid >> 6, l = tid & 63, l16 = l & 15, quad = l >> 4;

    const unsigned short* kh_b = kh + (long)bh * 2048 * 64;
    const unsigned short* vh_b = vht + (long)bh * 64 * 2048;

    const unsigned short* qsrc = qh + ((long)bh * 2048 + qt * 128) * 64;
    bf16x8 qf[2][2];
    #pragma unroll
    for (int dd = 0; dd < 2; ++dd)
        #pragma unroll
        for (int i = 0; i < 2; ++i)
            qf[dd][i] = *(const bf16x8*)(qsrc + (w * 32 + i * 16 + l16) * 64 +
                                         dd * 32 + quad * 8);
    #pragma unroll
    for (int dd = 0; dd < 2; ++dd)
        #pragma unroll
        for (int i = 0; i < 2; ++i)
            asm volatile("" :: "v"(qf[dd][i]));

    auto stage_k = [&](const unsigned short* base, int buf) {
        #pragma unroll
        for (int rr = 0; rr < 2; ++rr) {
            int sb = rr * 256 + w * 64;
            int slot = sb + l;
            int row = slot >> 3, cc = (slot & 7) ^ (row & 7);
            GLL16(base + (long)row * 64 + cc * 8, &Kb[buf][sb * 8]);
        }
    };
    auto stage_v = [&](const unsigned short* vbase, int buf) {
        #pragma unroll
        for (int rr = 0; rr < 2; ++rr) {
            int sb = rr * 256 + w * 64;
            int slot = sb + l;
            int d = slot >> 3, cc = (slot & 7) ^ (d & 7);
            GLL16(vbase + (long)d * 2048 + cc * 8, &Vb[buf][sb * 8]);
        }
    };

    // prologue: K0, V0, V1 issued; wait K0+V0 (vmcnt(2) leaves V1 in flight)
    stage_k(kh_b, 0);
    stage_v(vh_b, 0);
    stage_v(vh_b + 64, 1);
    asm volatile("s_waitcnt vmcnt(2)" ::: "memory");
    __builtin_amdgcn_s_barrier();
    __builtin_amdgcn_sched_barrier(0);

    f32x4 o[4][2] = {};
    f32x4 osum[2] = {};
    bf16x8 ones;
    #pragma unroll
    for (int j = 0; j < 8; ++j) ones[j] = (short)0x3f80;  // bf16 1.0

    const unsigned short* kstage = kh_b + 64 * 64;   // K[1] base
    const unsigned short* vstage = vh_b + 2 * 64;    // V[2] base
    int vr = 0, vs = 2;  // V read / stage buffer (mod 3)
    for (int kt = 0; kt < 32; ++kt) {
        if (kt < 31) stage_k(kstage, (kt + 1) & 1);
        if (kt < 30) stage_v(vstage, vs);
        kstage += 64 * 64;
        vstage += 64;
        __builtin_amdgcn_sched_barrier(0);  // keep prefetch issue at loop top

        const unsigned short* kb = Kb[kt & 1];
        f32x4 sa[2][4] = {};
        #pragma unroll
        for (int dd = 0; dd < 2; ++dd) {
            bf16x8 kf[4];
            #pragma unroll
            for (int ja = 0; ja < 4; ++ja) {
                int row = ja * 16 + l16;
                kf[ja] = *(const bf16x8*)(kb + (row * 8 + ((dd * 4 + quad) ^ (row & 7))) * 8);
            }
            __builtin_amdgcn_s_setprio(1);
            #pragma unroll
            for (int i = 0; i < 2; ++i)
                #pragma unroll
                for (int ja = 0; ja < 4; ++ja)
                    sa[i][ja] = mfma16(kf[ja], qf[dd][i], sa[i][ja]);
            __builtin_amdgcn_s_setprio(0);
        }

        #pragma unroll
        for (int i = 0; i < 2; ++i)
            #pragma unroll
            for (int ja = 0; ja < 4; ++ja)
                #pragma unroll
                for (int r = 0; r < 4; ++r)
                    sa[i][ja][r] = fexp2(sa[i][ja][r]);

        // no barrier: V[kt] resident since end of kt-1; Vb[vs] is a
        // different buffer ((kt+2)%3 != kt%3).
        const unsigned short* vb = Vb[vr];
        #pragma unroll
        for (int qtr = 0; qtr < 2; ++qtr) {
            #pragma unroll
            for (int jh = 0; jh < 2; ++jh)
                #pragma unroll
                for (int i = 0; i < 2; ++i) {
                    int row = w * 32 + i * 16 + l16;
                    int ja = qtr * 2 + jh;
                    uint2 pk;
                    pk.x = pkbf16(sa[i][ja][0], sa[i][ja][1]);
                    pk.y = pkbf16(sa[i][ja][2], sa[i][ja][3]);
                    *(uint2*)(&P[row * 44 + jh * 16 + quad * 4]) = pk;
                }
            bf16x8 vf[4], pf[2];
            #pragma unroll
            for (int jd = 0; jd < 4; ++jd) {
                int d = jd * 16 + l16;
                vf[jd] = *(const bf16x8*)(vb + (d * 8 + ((qtr * 4 + quad) ^ (d & 7))) * 8);
            }
            #pragma unroll
            for (int i = 0; i < 2; ++i) {
                int row = w * 32 + i * 16 + l16;
                pf[i] = *(const bf16x8*)(&P[row * 44 + quad * 8]);
            }
            __builtin_amdgcn_s_setprio(1);
            #pragma unroll
            for (int jd = 0; jd < 4; ++jd)
                #pragma unroll
                for (int i = 0; i < 2; ++i)
                    o[jd][i] = mfma16(vf[jd], pf[i], o[jd][i]);
            #pragma unroll
            for (int i = 0; i < 2; ++i)
                osum[i] = mfma16(ones, pf[i], osum[i]);  // row-sum on MFMA pipe
            __builtin_amdgcn_s_setprio(0);
        }

        // end-of-kt sync: wait K[kt+1]+V[kt+1] landed, keep V[kt+2] in flight
        if (kt < 30) {
            asm volatile("s_waitcnt vmcnt(2)" ::: "memory");
        } else if (kt == 30) {
            asm volatile("s_waitcnt vmcnt(0)" ::: "memory");
        }
        if (kt < 31) {
            __builtin_amdgcn_s_barrier();
            __builtin_amdgcn_sched_barrier(0);
        }

        vr = (vr + 1 == 3) ? 0 : vr + 1;
        vs = (vs + 1 == 3) ? 0 : vs + 1;
    }

    const int b = bh >> 4, hh = bh & 15;
    #pragma unroll
    for (int i = 0; i < 2; ++i) {
        float inv = 1.0f / osum[i][0];  // rows of osum all equal; col = l16 = q
        int s = qt * 128 + w * 32 + i * 16 + l16;
        #pragma unroll
        for (int jd = 0; jd < 4; ++jd) {
            uint2 pk;
            pk.x = pkbf16(o[jd][i][0] * inv, o[jd][i][1] * inv);
            pk.y = pkbf16(o[jd][i][2] * inv, o[jd][i][3] * inv);
            *(uint2*)(&ctx[((long)(b * 2048 + s) * 1024) + hh * 64 + jd * 16 + quad * 4]) = pk;
        }
    }
}

extern "C" void kernel_launch(void* const* d_in, const int* in_sizes, int n_in,
                              void* d_out, int out_size, void* d_ws, size_t ws_size,
                              hipStream_t stream) {
    const float* q  = (const float*)d_in[0];
    const float* k  = (const float*)d_in[1];
    const float* v  = (const float*)d_in[2];
    const float* wq = (const float*)d_in[3];
    const float* bq = (const float*)d_in[4];
    const float* wk = (const float*)d_in[5];
    const float* bk = (const float*)d_in[6];
    const float* wv = (const float*)d_in[7];
    const float* bv = (const float*)d_in[8];
    const float* wo = (const float*)d_in[9];
    const float* bo = (const float*)d_in[10];
    float* out = (float*)d_out;

    // workspace (u16 units): ctx(8M) | qh(8M) | kh(8M) | vht(8M) |
    // weights 4x1M = 36M u16 = 72 MB. (A-side bf16 staging buffers gone:
    // gemm_qkv reads q/k/v fp32 directly.)
    const size_t NE = 8u * 1024u * 1024u;
    unsigned short* ctx  = (unsigned short*)d_ws;
    unsigned short* qh   = ctx + NE;
    unsigned short* kh   = qh + NE;
    unsigned short* vht  = kh + NE;
    unsigned short* wb   = vht + NE;
    unsigned short* wob  = wb + 3 * 1048576;

    cvt_w<<<dim3(512, 4), dim3(256), 0, stream>>>(wq, wk, wv, wo, wb);
    gemm_qkv<<<dim3(8, 32, 3), dim3(512), 0, stream>>>(q, k, v, wb,
                                                       bq, bk, bv, qh, kh, vht);
    attn<<<dim3(16, 64), dim3(256), 0, stream>>>(qh, kh, vht, ctx);
    gemm_out<<<dim3(8, 32), dim3(512), 0, stream>>>(ctx, wob, bo, out);
}